// Round 11
// baseline (195.396 us; speedup 1.0000x reference)
//
#include <hip/hip_runtime.h>
#include <hip/hip_bf16.h>
#include <stdint.h>

// SelfBallPointQuery: B=16, C=3, N=2048, RADIUS^2=0.04, MAX_SAMPLES=64.
// R11 = R10's transposed-bitset test phase (lane=query, ~12 VALU / 64 pairs)
// with the emit fixed: R10's per-lane global scatter caused 9x write
// amplification (77 MB WRITE, 11 MB FETCH from read-for-ownership on partial
// lines) and went HBM-bound. Now hits are emitted into an LDS row buffer
// (stride 65 to spread banks) and copied out fully coalesced. Also 16 waves x
// 1024 threads -> 32 waves/CU (was 16) for latency hiding.

#define B_DIM 16
#define N_PTS 2048
#define K_OUT 64
#define R2 0.04f
#define WAVES 16
#define BLOCK_T (WAVES * 64)            // 1024
#define JPW (N_PTS / WAVES)             // 128 points per wave
#define WPW (JPW / 32)                  // 4 mask words per lane
#define ROWPAD 65                       // LDS row stride (bank spread)

__global__ __launch_bounds__(BLOCK_T, 8) void ball_query_kernel(
    const float* __restrict__ pcs,   // (B, 3, N)
    int* __restrict__ out)           // (B, N, 64) int32
{
    __shared__ float xs4[N_PTS * 4];        // 32 KB
    __shared__ int   rows[64 * ROWPAD];     // 16.25 KB output staging
    __shared__ int   cntS[WAVES][64];       // 4 KB
    __shared__ int   qfS[WAVES][64];        // 4 KB

    const int b    = blockIdx.x >> 5;        // / 32
    const int qg   = blockIdx.x & 31;        // query group (64 queries)
    const int tid  = threadIdx.x;
    const int wave = tid >> 6;
    const int lane = tid & 63;

    // Stage cloud b as float4 per point
    const float* src = pcs + (size_t)b * 3 * N_PTS;
    for (int j = tid; j < N_PTS; j += BLOCK_T) {
        float4 p;
        p.x = src[0 * N_PTS + j];
        p.y = src[1 * N_PTS + j];
        p.z = src[2 * N_PTS + j];
        p.w = 0.0f;
        *(float4*)&xs4[j * 4] = p;
    }
    __syncthreads();

    // my query = lane-th query of this group (same for all waves)
    const int qi = qg * 64 + lane;
    const float qx = xs4[qi * 4 + 0];
    const float qy = xs4[qi * 4 + 1];
    const float qz = xs4[qi * 4 + 2];

    const int jbase = wave * JPW;

    // ---- dense test phase: 4 words x 32 bits per lane ----
    unsigned mask[WPW];
    #pragma unroll
    for (int t = 0; t < WPW; ++t) {
        unsigned m = 0;
        #pragma unroll
        for (int k = 31; k >= 0; --k) {       // descending: bit k = point +k
            const int j = jbase + t * 32 + k;
            const float4 p = *(const float4*)&xs4[j * 4];  // wave-uniform bcast
            const float dx = p.x - qx;
            const float dy = p.y - qy;
            const float dz = p.z - qz;
            // exact numpy f32 association, no FMA contraction:
            const float d2 = __fadd_rn(__fadd_rn(__fmul_rn(dx, dx),
                                                 __fmul_rn(dy, dy)),
                                       __fmul_rn(dz, dz));
            m = m + m + (unsigned)(d2 < R2);
        }
        mask[t] = m;
    }

    // per-lane count + first hit within this wave's window
    int cnt = 0;
    #pragma unroll
    for (int t = 0; t < WPW; ++t) cnt += __builtin_popcount(mask[t]);
    int qf = -1;
    #pragma unroll
    for (int t = 0; t < WPW; ++t) {
        if (qf < 0 && mask[t] != 0u)
            qf = jbase + t * 32 + __builtin_ctz(mask[t]);
    }
    cntS[wave][lane] = cnt;
    qfS[wave][lane]  = qf;
    __syncthreads();

    // prefix over earlier waves' counts for my query; global first hit
    int base = 0, tc = 0, gfirst = 0;
    #pragma unroll
    for (int w = 0; w < WAVES; ++w) {
        const int c = cntS[w][lane];
        const int f = qfS[w][lane];
        if (w < wave) base += c;
        gfirst = (tc == 0 && c > 0) ? f : gfirst;
        tc += c;
    }

    // ---- sparse emit into LDS rows (disjoint slot ranges across waves) ----
    int slot = base;
    #pragma unroll
    for (int t = 0; t < WPW; ++t) {
        unsigned m = mask[t];
        while (m != 0u && slot < K_OUT) {
            const int k = (int)__builtin_ctz(m);
            rows[lane * ROWPAD + slot] = jbase + t * 32 + k;
            m &= m - 1u;
            ++slot;
        }
    }

    // ---- pad: 4 slots per wave cover [0,64); fill gfirst where s >= tc ----
    #pragma unroll
    for (int s0 = 0; s0 < K_OUT / WAVES; ++s0) {
        const int s = wave * (K_OUT / WAVES) + s0;
        if (s >= tc) rows[lane * ROWPAD + s] = gfirst;
    }
    __syncthreads();

    // ---- coalesced copy-out: 64 rows x 64 ints, consecutive tid -> addr ----
    int* const obase = out + (size_t)(b * N_PTS + qg * 64) * K_OUT;
    #pragma unroll
    for (int it = 0; it < (64 * K_OUT) / BLOCK_T; ++it) {
        const int idx = it * BLOCK_T + tid;
        const int r = idx >> 6;
        const int c = idx & 63;
        obase[idx] = rows[r * ROWPAD + c];
    }
}

extern "C" void kernel_launch(void* const* d_in, const int* in_sizes, int n_in,
                              void* d_out, int out_size, void* d_ws, size_t ws_size,
                              hipStream_t stream) {
    const float* pcs = (const float*)d_in[0];
    int* out = (int*)d_out;
    const int grid = B_DIM * 32;     // 512 blocks (16 batches x 32 query groups)
    ball_query_kernel<<<grid, BLOCK_T, 0, stream>>>(pcs, out);
}

// Round 12
// 82.192 us; speedup vs baseline: 2.3773x; 2.3773x over previous
//
#include <hip/hip_runtime.h>
#include <hip/hip_bf16.h>
#include <stdint.h>

// SelfBallPointQuery: B=16, C=3, N=2048, RADIUS^2=0.04, MAX_SAMPLES=64.
// R12 = transposed-bitset test (lane=query, ~11 VALU / 64 pairs) + LDS-staged
// emit + coalesced copy-out.
// R11 post-mortem: __launch_bounds__(1024,8) clamped the allocator to 32 VGPR
// -> mask/emit state spilled to scratch (HBM): 480 MB of spill traffic,
// VALUBusy 0.2%. R12 reverts to R10's proven shape (8 waves x 512 thr,
// 64 VGPR, no spill) and keeps the LDS emit that fixed R10's 9x write
// amplification. LDS 52.25 KB -> 3 blocks/CU = 24 waves/CU.

#define B_DIM 16
#define N_PTS 2048
#define K_OUT 64
#define R2 0.04f
#define WAVES 8
#define BLOCK_T (WAVES * 64)            // 512
#define JPW (N_PTS / WAVES)             // 256 points per wave
#define WPW (JPW / 32)                  // 8 mask words per lane
#define ROWPAD 65                       // LDS row stride (bank spread for scatter)

__global__ __launch_bounds__(BLOCK_T, 6) void ball_query_kernel(
    const float* __restrict__ pcs,   // (B, 3, N)
    int* __restrict__ out)           // (B, N, 64) int32
{
    __shared__ float xs4[N_PTS * 4];        // 32 KB
    __shared__ int   rows[64 * ROWPAD];     // 16.25 KB output staging
    __shared__ int   cntS[WAVES][64];       // 2 KB
    __shared__ int   qfS[WAVES][64];        // 2 KB

    const int b    = blockIdx.x >> 5;        // / 32
    const int qg   = blockIdx.x & 31;        // query group (64 queries)
    const int tid  = threadIdx.x;
    const int wave = tid >> 6;
    const int lane = tid & 63;

    // Stage cloud b as float4 per point
    const float* src = pcs + (size_t)b * 3 * N_PTS;
    for (int j = tid; j < N_PTS; j += BLOCK_T) {
        float4 p;
        p.x = src[0 * N_PTS + j];
        p.y = src[1 * N_PTS + j];
        p.z = src[2 * N_PTS + j];
        p.w = 0.0f;
        *(float4*)&xs4[j * 4] = p;
    }
    __syncthreads();

    // my query = lane-th query of this group (same for all waves)
    const int qi = qg * 64 + lane;
    const float qx = xs4[qi * 4 + 0];
    const float qy = xs4[qi * 4 + 1];
    const float qz = xs4[qi * 4 + 2];

    const int jbase = wave * JPW;

    // ---- dense test phase: 8 words x 32 bits per lane ----
    unsigned mask[WPW];
    for (int t = 0; t < WPW; ++t) {
        unsigned m = 0;
        #pragma unroll
        for (int k = 31; k >= 0; --k) {       // descending: bit k = point +k
            const int j = jbase + t * 32 + k;
            const float4 p = *(const float4*)&xs4[j * 4];  // wave-uniform bcast
            const float dx = p.x - qx;
            const float dy = p.y - qy;
            const float dz = p.z - qz;
            // exact numpy f32 association, no FMA contraction:
            const float d2 = __fadd_rn(__fadd_rn(__fmul_rn(dx, dx),
                                                 __fmul_rn(dy, dy)),
                                       __fmul_rn(dz, dz));
            m = m + m + (unsigned)(d2 < R2);
        }
        mask[t] = m;
    }

    // per-lane count + first hit within this wave's window
    int cnt = 0;
    #pragma unroll
    for (int t = 0; t < WPW; ++t) cnt += __builtin_popcount(mask[t]);
    int qf = -1;
    #pragma unroll
    for (int t = 0; t < WPW; ++t) {
        if (qf < 0 && mask[t] != 0u)
            qf = jbase + t * 32 + __builtin_ctz(mask[t]);
    }
    cntS[wave][lane] = cnt;
    qfS[wave][lane]  = qf;
    __syncthreads();

    // prefix over earlier waves' counts for my query; global first hit
    int base = 0, tc = 0, gfirst = 0;
    #pragma unroll
    for (int w = 0; w < WAVES; ++w) {
        const int c = cntS[w][lane];
        const int f = qfS[w][lane];
        if (w < wave) base += c;
        gfirst = (tc == 0 && c > 0) ? f : gfirst;
        tc += c;
    }

    // ---- sparse emit into LDS rows (disjoint slot ranges across waves) ----
    int slot = base;
    for (int t = 0; t < WPW; ++t) {
        unsigned m = mask[t];
        while (m != 0u && slot < K_OUT) {
            const int k = (int)__builtin_ctz(m);
            rows[lane * ROWPAD + slot] = jbase + t * 32 + k;
            m &= m - 1u;
            ++slot;
        }
    }

    // ---- pad: 8 slots per wave cover [0,64); fill gfirst where s >= tc ----
    #pragma unroll
    for (int s0 = 0; s0 < K_OUT / WAVES; ++s0) {
        const int s = wave * (K_OUT / WAVES) + s0;
        if (s >= tc) rows[lane * ROWPAD + s] = gfirst;
    }
    __syncthreads();

    // ---- coalesced copy-out: 64 rows x 64 ints, consecutive tid -> addr ----
    int* const obase = out + (size_t)(b * N_PTS + qg * 64) * K_OUT;
    #pragma unroll
    for (int it = 0; it < (64 * K_OUT) / BLOCK_T; ++it) {
        const int idx = it * BLOCK_T + tid;
        const int r = idx >> 6;
        const int c = idx & 63;
        obase[idx] = rows[r * ROWPAD + c];
    }
}

extern "C" void kernel_launch(void* const* d_in, const int* in_sizes, int n_in,
                              void* d_out, int out_size, void* d_ws, size_t ws_size,
                              hipStream_t stream) {
    const float* pcs = (const float*)d_in[0];
    int* out = (int*)d_out;
    const int grid = B_DIM * 32;     // 512 blocks (16 batches x 32 query groups)
    ball_query_kernel<<<grid, BLOCK_T, 0, stream>>>(pcs, out);
}

// Round 13
// 81.817 us; speedup vs baseline: 2.3882x; 1.0046x over previous
//
#include <hip/hip_runtime.h>
#include <hip/hip_bf16.h>
#include <stdint.h>

// SelfBallPointQuery: B=16, C=3, N=2048, RADIUS^2=0.04, MAX_SAMPLES=64.
// R13 = R12 (transposed bitset, LDS-staged emit, coalesced copy-out) with the
// test phase cut from ~11 to ~6 VALU/point:
//  - SoA LDS (xs/ys/zs) so 2 consecutive points' coords load as float2
//    (ds_read_b64) and feed full-rate packed v_pk_add/mul_f32 (VOP3P).
//  - 12 B/point LDS broadcast traffic instead of 16.
//  - FMA contraction blocked by pragma (packed ops are element-wise RN;
//    association (dx^2+dy^2)+dz^2 preserved; dx sign flip is square-exact).
// Occupancy is grid-limited (512 blocks = 2 blocks/CU x 8 waves); bound (512,4)
// gives the allocator a 128-VGPR budget -> no R11-style spill.

#define B_DIM 16
#define N_PTS 2048
#define K_OUT 64
#define R2 0.04f
#define WAVES 8
#define BLOCK_T (WAVES * 64)            // 512
#define JPW (N_PTS / WAVES)             // 256 points per wave
#define WPW (JPW / 32)                  // 8 mask words per lane
#define ROWPAD 65                       // LDS row stride (bank spread)

typedef float v2f __attribute__((ext_vector_type(2)));

__global__ __launch_bounds__(BLOCK_T, 4) void ball_query_kernel(
    const float* __restrict__ pcs,   // (B, 3, N)
    int* __restrict__ out)           // (B, N, 64) int32
{
#pragma clang fp contract(off)
    __shared__ float xs[N_PTS];             // 8 KB
    __shared__ float ys[N_PTS];             // 8 KB
    __shared__ float zs[N_PTS];             // 8 KB
    __shared__ int   rows[64 * ROWPAD];     // 16.25 KB output staging
    __shared__ int   cntS[WAVES][64];       // 2 KB
    __shared__ int   qfS[WAVES][64];        // 2 KB

    const int b    = blockIdx.x >> 5;        // / 32
    const int qg   = blockIdx.x & 31;        // query group (64 queries)
    const int tid  = threadIdx.x;
    const int wave = tid >> 6;
    const int lane = tid & 63;

    // Stage cloud b as SoA (coalesced global reads, stride-1 LDS writes)
    const float* src = pcs + (size_t)b * 3 * N_PTS;
    for (int j = tid; j < N_PTS; j += BLOCK_T) {
        xs[j] = src[0 * N_PTS + j];
        ys[j] = src[1 * N_PTS + j];
        zs[j] = src[2 * N_PTS + j];
    }
    __syncthreads();

    // my query = lane-th query of this group (same for all waves)
    const int qi = qg * 64 + lane;
    const float qx = xs[qi];
    const float qy = ys[qi];
    const float qz = zs[qi];
    const v2f qx2 = {qx, qx}, qy2 = {qy, qy}, qz2 = {qz, qz};

    const int jbase = wave * JPW;

    // ---- dense test phase: 8 words x 32 bits per lane, 2 points/step ----
    unsigned mask[WPW];
    for (int t = 0; t < WPW; ++t) {
        unsigned m = 0;
        #pragma unroll
        for (int k = 30; k >= 0; k -= 2) {    // descending pairs: bits k+1, k
            const int j = jbase + t * 32 + k; // even -> 8B aligned
            const v2f px = *(const v2f*)&xs[j];   // ds_read_b64 (bcast)
            const v2f py = *(const v2f*)&ys[j];
            const v2f pz = *(const v2f*)&zs[j];
            const v2f dx = px - qx2;
            const v2f dy = py - qy2;
            const v2f dz = pz - qz2;
            const v2f d2 = (dx * dx + dy * dy) + dz * dz;  // pk ops, no fma
            // bit k+1 (point j+1) first, then bit k (point j)
            m = m + m + (unsigned)(d2.y < R2);
            m = m + m + (unsigned)(d2.x < R2);
        }
        mask[t] = m;
    }

    // per-lane count + first hit within this wave's window
    int cnt = 0;
    #pragma unroll
    for (int t = 0; t < WPW; ++t) cnt += __builtin_popcount(mask[t]);
    int qf = -1;
    #pragma unroll
    for (int t = 0; t < WPW; ++t) {
        if (qf < 0 && mask[t] != 0u)
            qf = jbase + t * 32 + __builtin_ctz(mask[t]);
    }
    cntS[wave][lane] = cnt;
    qfS[wave][lane]  = qf;
    __syncthreads();

    // prefix over earlier waves' counts for my query; global first hit
    int base = 0, tc = 0, gfirst = 0;
    #pragma unroll
    for (int w = 0; w < WAVES; ++w) {
        const int c = cntS[w][lane];
        const int f = qfS[w][lane];
        if (w < wave) base += c;
        gfirst = (tc == 0 && c > 0) ? f : gfirst;
        tc += c;
    }

    // ---- sparse emit into LDS rows (disjoint slot ranges across waves) ----
    int slot = base;
    for (int t = 0; t < WPW; ++t) {
        unsigned m = mask[t];
        while (m != 0u && slot < K_OUT) {
            const int k = (int)__builtin_ctz(m);
            rows[lane * ROWPAD + slot] = jbase + t * 32 + k;
            m &= m - 1u;
            ++slot;
        }
    }

    // ---- pad: 8 slots per wave cover [0,64); fill gfirst where s >= tc ----
    #pragma unroll
    for (int s0 = 0; s0 < K_OUT / WAVES; ++s0) {
        const int s = wave * (K_OUT / WAVES) + s0;
        if (s >= tc) rows[lane * ROWPAD + s] = gfirst;
    }
    __syncthreads();

    // ---- coalesced copy-out: 64 rows x 64 ints, consecutive tid -> addr ----
    int* const obase = out + (size_t)(b * N_PTS + qg * 64) * K_OUT;
    #pragma unroll
    for (int it = 0; it < (64 * K_OUT) / BLOCK_T; ++it) {
        const int idx = it * BLOCK_T + tid;
        const int r = idx >> 6;
        const int c = idx & 63;
        obase[idx] = rows[r * ROWPAD + c];
    }
}

extern "C" void kernel_launch(void* const* d_in, const int* in_sizes, int n_in,
                              void* d_out, int out_size, void* d_ws, size_t ws_size,
                              hipStream_t stream) {
    const float* pcs = (const float*)d_in[0];
    int* out = (int*)d_out;
    const int grid = B_DIM * 32;     // 512 blocks (16 batches x 32 query groups)
    ball_query_kernel<<<grid, BLOCK_T, 0, stream>>>(pcs, out);
}

// Round 14
// 76.130 us; speedup vs baseline: 2.5666x; 1.0747x over previous
//
#include <hip/hip_runtime.h>
#include <hip/hip_bf16.h>
#include <stdint.h>

// SelfBallPointQuery: B=16, C=3, N=2048, RADIUS^2=0.04, MAX_SAMPLES=64.
// R14: points via the SCALAR pipe. R12/R13 post-mortem: test phase was bound
// by LDS broadcast (64x return-bus waste delivering the same point to all
// lanes; ~9-12 LDS-pipe cyc/point, ~15us/CU floor). Point index j is
// wave-uniform -> readfirstlane(wave) makes LLVM's divergence analysis see it,
// so point loads lower to s_load_dwordx8/x16 (SGPR file = the architectural
// broadcast store). Inner loop: SGPR-pair point coords feed packed
// v_pk_*_f32 against per-lane query VGPRs. No LDS staging of the cloud at
// all; LDS keeps only the output staging (rows) + per-wave counts
// (~20.6 KB -> 4 blocks/CU = 32 waves/CU at VGPR<=64).

#define B_DIM 16
#define N_PTS 2048
#define K_OUT 64
#define R2 0.04f
#define WAVES 8
#define BLOCK_T (WAVES * 64)            // 512
#define JPW (N_PTS / WAVES)             // 256 points per wave
#define WPW (JPW / 32)                  // 8 mask words per lane
#define ROWPAD 65                       // LDS row stride (bank spread)

typedef float v2f __attribute__((ext_vector_type(2)));

__global__ __launch_bounds__(BLOCK_T, 8) void ball_query_kernel(
    const float* __restrict__ pcs,   // (B, 3, N)
    int* __restrict__ out)           // (B, N, 64) int32
{
#pragma clang fp contract(off)
    __shared__ int rows[64 * ROWPAD];       // 16.64 KB output staging
    __shared__ int cntS[WAVES][64];         // 2 KB
    __shared__ int qfS[WAVES][64];          // 2 KB

    const int b    = blockIdx.x >> 5;        // / 32
    const int qg   = blockIdx.x & 31;        // query group (64 queries)
    const int tid  = threadIdx.x;
    // readfirstlane -> compiler-visible wave-uniform value => j is uniform
    // => point loads select to SMEM (s_load), not VMEM/LDS.
    const int wave = __builtin_amdgcn_readfirstlane(tid >> 6);
    const int lane = tid & 63;

    const float* __restrict__ sx = pcs + (size_t)b * 3 * N_PTS;
    const float* __restrict__ sy = sx + N_PTS;
    const float* __restrict__ sz = sy + N_PTS;

    // my query = lane-th query of this group (coalesced vector loads)
    const int qi = qg * 64 + lane;
    const float qx = sx[qi];
    const float qy = sy[qi];
    const float qz = sz[qi];
    const v2f qx2 = {qx, qx}, qy2 = {qy, qy}, qz2 = {qz, qz};

    const int jbase = wave * JPW;

    // ---- dense test phase: 8 words x 32 bits per lane, 2 points/step ----
    unsigned mask[WPW];
    for (int t = 0; t < WPW; ++t) {
        unsigned m = 0;
        #pragma unroll
        for (int k = 30; k >= 0; k -= 2) {    // descending pairs: bits k+1, k
            const int j = jbase + t * 32 + k; // wave-uniform, even (8B align)
            const v2f px = *(const v2f*)(sx + j);   // uniform -> s_load
            const v2f py = *(const v2f*)(sy + j);
            const v2f pz = *(const v2f*)(sz + j);
            const v2f dx = px - qx2;          // v_pk_add_f32 (s-pair, -v-pair)
            const v2f dy = py - qy2;
            const v2f dz = pz - qz2;
            const v2f d2 = (dx * dx + dy * dy) + dz * dz;  // pk, contract off
            // bit k+1 (point j+1) first, then bit k (point j)
            m = m + m + (unsigned)(d2.y < R2);
            m = m + m + (unsigned)(d2.x < R2);
        }
        mask[t] = m;
    }

    // per-lane count + first hit within this wave's window
    int cnt = 0;
    #pragma unroll
    for (int t = 0; t < WPW; ++t) cnt += __builtin_popcount(mask[t]);
    int qf = -1;
    #pragma unroll
    for (int t = 0; t < WPW; ++t) {
        if (qf < 0 && mask[t] != 0u)
            qf = jbase + t * 32 + __builtin_ctz(mask[t]);
    }
    cntS[wave][lane] = cnt;
    qfS[wave][lane]  = qf;
    __syncthreads();

    // prefix over earlier waves' counts for my query; global first hit
    int base = 0, tc = 0, gfirst = 0;
    #pragma unroll
    for (int w = 0; w < WAVES; ++w) {
        const int c = cntS[w][lane];
        const int f = qfS[w][lane];
        if (w < wave) base += c;
        gfirst = (tc == 0 && c > 0) ? f : gfirst;
        tc += c;
    }

    // ---- sparse emit into LDS rows (disjoint slot ranges across waves) ----
    int slot = base;
    for (int t = 0; t < WPW; ++t) {
        unsigned m = mask[t];
        while (m != 0u && slot < K_OUT) {
            const int k = (int)__builtin_ctz(m);
            rows[lane * ROWPAD + slot] = jbase + t * 32 + k;
            m &= m - 1u;
            ++slot;
        }
    }

    // ---- pad: 8 slots per wave cover [0,64); fill gfirst where s >= tc ----
    #pragma unroll
    for (int s0 = 0; s0 < K_OUT / WAVES; ++s0) {
        const int s = wave * (K_OUT / WAVES) + s0;
        if (s >= tc) rows[lane * ROWPAD + s] = gfirst;
    }
    __syncthreads();

    // ---- coalesced copy-out: 64 rows x 64 ints, consecutive tid -> addr ----
    int* const obase = out + (size_t)(b * N_PTS + qg * 64) * K_OUT;
    #pragma unroll
    for (int it = 0; it < (64 * K_OUT) / BLOCK_T; ++it) {
        const int idx = it * BLOCK_T + tid;
        const int r = idx >> 6;
        const int c = idx & 63;
        obase[idx] = rows[r * ROWPAD + c];
    }
}

extern "C" void kernel_launch(void* const* d_in, const int* in_sizes, int n_in,
                              void* d_out, int out_size, void* d_ws, size_t ws_size,
                              hipStream_t stream) {
    const float* pcs = (const float*)d_in[0];
    int* out = (int*)d_out;
    const int grid = B_DIM * 32;     // 512 blocks (16 batches x 32 query groups)
    ball_query_kernel<<<grid, BLOCK_T, 0, stream>>>(pcs, out);
}